// Round 4
// baseline (1262.366 us; speedup 1.0000x reference)
//
#include <hip/hip_runtime.h>

#define NN 100000
#define NE 3200000
#define F_IN 21
#define HID 64
#define EPS 1e-5f

// ---------------- CSR build ----------------

__global__ void kA_count(const int* __restrict__ dst, int* __restrict__ cnt,
                         int* __restrict__ slot) {
    int i = blockIdx.x * blockDim.x + threadIdx.x;
    int st = gridDim.x * blockDim.x;
    for (int e = i; e < NE; e += st) slot[e] = atomicAdd(&cnt[dst[e]], 1);
}

__global__ void kB_scan(const int* __restrict__ cnt, int* __restrict__ rowptr) {
    __shared__ int lds[1024];
    int t = threadIdx.x;
    const int CH = 100;  // 1000 threads x 100 = 100000
    int lo = t * CH;
    int s = 0;
    if (lo < NN) {
        const int4* p = (const int4*)(cnt + lo);
#pragma unroll
        for (int i = 0; i < CH / 4; ++i) { int4 v = p[i]; s += v.x + v.y + v.z + v.w; }
    }
    lds[t] = s;
    __syncthreads();
    for (int off = 1; off < 1024; off <<= 1) {
        int v = (t >= off) ? lds[t - off] : 0;
        __syncthreads();
        lds[t] += v;
        __syncthreads();
    }
    if (lo < NN) {
        int run = lds[t] - s;  // exclusive prefix
        for (int i = lo; i < lo + CH; ++i) { rowptr[i] = run; run += cnt[i]; }
    }
    if (t == 0) rowptr[NN] = NE;
}

// one 16B aligned scatter per edge: {src_bits, a0, a1, a2}
__global__ void kC_fill(const int* __restrict__ src, const int* __restrict__ dst,
                        const float* __restrict__ eattr,
                        const int* __restrict__ rowptr, const int* __restrict__ slot,
                        float4* __restrict__ pack) {
    int i = blockIdx.x * blockDim.x + threadIdx.x;
    int st = gridDim.x * blockDim.x;
    for (int e = i; e < NE; e += st) {
        int d = dst[e];
        int pos = rowptr[d] + slot[e];
        size_t eb = (size_t)e * 3;
        float4 pk;
        pk.x = __int_as_float(src[e]);
        pk.y = eattr[eb];
        pk.z = eattr[eb + 1];
        pk.w = eattr[eb + 2];
        pack[pos] = pk;
    }
}

// coalesced extraction of csr_src from the pack (runs after gather1)
__global__ void kD_strip(const int4* __restrict__ pack, int* __restrict__ csr_src) {
    int i = blockIdx.x * blockDim.x + threadIdx.x;
    int st = gridDim.x * blockDim.x;
    for (int e = i; e < NE; e += st) csr_src[e] = pack[e].x;
}

// ---------------- pre1: yl = x@W1l.T ; own(h1 init) = x@W1r.T + b1 ----------------

__global__ void __launch_bounds__(256, 4) kE_pre1(
    const float* __restrict__ x, const float* __restrict__ W1l,
    const float* __restrict__ b1l, const float* __restrict__ W1r,
    float* __restrict__ yl, float* __restrict__ own) {
    int lane = threadIdx.x & 63;
    int gw = blockIdx.x * 4 + (threadIdx.x >> 6);
    int nw = gridDim.x * 4;
    float wl[F_IN], wr[F_IN];
#pragma unroll
    for (int k = 0; k < F_IN; ++k) {
        wl[k] = W1l[lane * F_IN + k];
        wr[k] = W1r[lane * F_IN + k];
    }
    float b = b1l[lane];
    for (int n = gw; n < NN; n += nw) {
        float xv = (lane < F_IN) ? x[(size_t)n * F_IN + lane] : 0.f;
        float sy = 0.f, so = b;
#pragma unroll
        for (int k = 0; k < F_IN; ++k) {
            float xk = __shfl(xv, k);
            sy = fmaf(wl[k], xk, sy);
            so = fmaf(wr[k], xk, so);
        }
        yl[(size_t)n * HID + lane] = sy;
        own[(size_t)n * HID + lane] = so;
    }
}

// ---------------- gather1: h1 = own + mean(yl[src]) + sum(relu(We@attr+be)) ------
// wave per node; 4 groups x 16 lanes; lane holds channel quad 4*c4..+3

#define GRED(v) { v += __shfl_xor(v, 16); v += __shfl_xor(v, 32); }

__global__ void __launch_bounds__(256, 8) kF_gather1(
    const float* __restrict__ yl, const float4* __restrict__ pack,
    const int* __restrict__ rowptr,
    const float* __restrict__ We, const float* __restrict__ be,
    float* __restrict__ H1, float* __restrict__ gsum, float* __restrict__ gsq) {
    int lane = threadIdx.x & 63;
    int g = lane >> 4, c4 = lane & 15;
    int gw = blockIdx.x * 4 + (threadIdx.x >> 6);
    int nw = gridDim.x * 4;

    float wa0 = We[(4 * c4 + 0) * 3], wb0 = We[(4 * c4 + 0) * 3 + 1], wc0 = We[(4 * c4 + 0) * 3 + 2];
    float wa1 = We[(4 * c4 + 1) * 3], wb1 = We[(4 * c4 + 1) * 3 + 1], wc1 = We[(4 * c4 + 1) * 3 + 2];
    float wa2 = We[(4 * c4 + 2) * 3], wb2 = We[(4 * c4 + 2) * 3 + 1], wc2 = We[(4 * c4 + 2) * 3 + 2];
    float wa3 = We[(4 * c4 + 3) * 3], wb3 = We[(4 * c4 + 3) * 3 + 1], wc3 = We[(4 * c4 + 3) * 3 + 2];
    float bq0 = be[4 * c4 + 0], bq1 = be[4 * c4 + 1], bq2 = be[4 * c4 + 2], bq3 = be[4 * c4 + 3];

    float ps0 = 0, ps1 = 0, ps2 = 0, ps3 = 0, pq0 = 0, pq1 = 0, pq2 = 0, pq3 = 0;

    for (int n = gw; n < NN; n += nw) {
        int beg = rowptr[n], end = rowptr[n + 1];
        float aY0 = 0, aY1 = 0, aY2 = 0, aY3 = 0;
        float aE0 = 0, aE1 = 0, aE2 = 0, aE3 = 0;
        for (int p0 = beg; p0 < end; p0 += 64) {
            int cntj = min(64, end - p0);
            float4 pkL = {0.f, 0.f, 0.f, 0.f};
            if (lane < cntj) pkL = pack[p0 + lane];
            int jm = (cntj + 3) >> 2;
#pragma unroll 4
            for (int j = 0; j < jm; ++j) {
                int idx = j * 4 + g;
                int s = __float_as_int(__shfl(pkL.x, idx));
                float a0 = __shfl(pkL.y, idx);
                float a1 = __shfl(pkL.z, idx);
                float a2 = __shfl(pkL.w, idx);
                float m = (idx < cntj) ? 1.f : 0.f;
                const float4 y = *(const float4*)(yl + (size_t)s * HID + 4 * c4);
                aY0 = fmaf(y.x, m, aY0);
                aY1 = fmaf(y.y, m, aY1);
                aY2 = fmaf(y.z, m, aY2);
                aY3 = fmaf(y.w, m, aY3);
                float e0 = fmaf(wa0, a0, fmaf(wb0, a1, fmaf(wc0, a2, bq0)));
                float e1 = fmaf(wa1, a0, fmaf(wb1, a1, fmaf(wc1, a2, bq1)));
                float e2 = fmaf(wa2, a0, fmaf(wb2, a1, fmaf(wc2, a2, bq2)));
                float e3 = fmaf(wa3, a0, fmaf(wb3, a1, fmaf(wc3, a2, bq3)));
                aE0 = fmaf(fmaxf(e0, 0.f), m, aE0);
                aE1 = fmaf(fmaxf(e1, 0.f), m, aE1);
                aE2 = fmaf(fmaxf(e2, 0.f), m, aE2);
                aE3 = fmaf(fmaxf(e3, 0.f), m, aE3);
            }
        }
        GRED(aY0) GRED(aY1) GRED(aY2) GRED(aY3)
        GRED(aE0) GRED(aE1) GRED(aE2) GRED(aE3)
        if (g == 0) {
            float invd = 1.f / fmaxf((float)(end - beg), 1.f);
            const float4 own = *(const float4*)(H1 + (size_t)n * HID + 4 * c4);
            float h0 = fmaf(aY0, invd, own.x) + aE0;
            float h1v = fmaf(aY1, invd, own.y) + aE1;
            float h2v = fmaf(aY2, invd, own.z) + aE2;
            float h3v = fmaf(aY3, invd, own.w) + aE3;
            float4 hv = {h0, h1v, h2v, h3v};
            *(float4*)(H1 + (size_t)n * HID + 4 * c4) = hv;
            ps0 += h0; ps1 += h1v; ps2 += h2v; ps3 += h3v;
            pq0 += h0 * h0; pq1 += h1v * h1v; pq2 += h2v * h2v; pq3 += h3v * h3v;
        }
    }
    __shared__ float bs[HID], bq[HID];
    if (threadIdx.x < HID) { bs[threadIdx.x] = 0.f; bq[threadIdx.x] = 0.f; }
    __syncthreads();
    if (g == 0) {
        atomicAdd(&bs[4 * c4 + 0], ps0); atomicAdd(&bq[4 * c4 + 0], pq0);
        atomicAdd(&bs[4 * c4 + 1], ps1); atomicAdd(&bq[4 * c4 + 1], pq1);
        atomicAdd(&bs[4 * c4 + 2], ps2); atomicAdd(&bq[4 * c4 + 2], pq2);
        atomicAdd(&bs[4 * c4 + 3], ps3); atomicAdd(&bq[4 * c4 + 3], pq3);
    }
    __syncthreads();
    if (threadIdx.x < HID) {
        atomicAdd(&gsum[threadIdx.x], bs[threadIdx.x]);
        atomicAdd(&gsq[threadIdx.x], bq[threadIdx.x]);
    }
}

// ---------------- BN finalize ----------------

__global__ void kG_bnstat(const float* __restrict__ gsum, const float* __restrict__ gsq,
                          const float* __restrict__ g, const float* __restrict__ beta,
                          float* __restrict__ scale, float* __restrict__ shift) {
    int c = threadIdx.x;
    if (c < HID) {
        float mu = gsum[c] * (1.f / (float)NN);
        float var = gsq[c] * (1.f / (float)NN) - mu * mu;
        float rstd = rsqrtf(var + EPS);
        float sc = rstd * g[c];
        scale[c] = sc;
        shift[c] = beta[c] - mu * sc;
    }
}

// ---------------- pre2: act=relu(bn(h1)); U=act@W2l.T; Z=act@W2r.T+b2 ----------------

__global__ void __launch_bounds__(256, 4) kH_pre2(
    const float* __restrict__ H1, const float* __restrict__ W2l,
    const float* __restrict__ W2r, const float* __restrict__ b2l,
    const float* __restrict__ sc1, const float* __restrict__ sh1,
    float* __restrict__ U, float* __restrict__ Z) {
    __shared__ float ldsL[HID * HID];  // [k][c]
    __shared__ float ldsR[HID * HID];
    for (int i = threadIdx.x; i < HID * HID; i += blockDim.x) {
        int k = i >> 6, c = i & 63;
        ldsL[i] = W2l[c * HID + k];
        ldsR[i] = W2r[c * HID + k];
    }
    __syncthreads();
    int lane = threadIdx.x & 63;
    int g = lane >> 4, c4 = lane & 15;
    int wv = blockIdx.x * 4 + (threadIdx.x >> 6);
    int nw = gridDim.x * 4;
    float4 sc = *(const float4*)(sc1 + 4 * c4);
    float4 sh = *(const float4*)(sh1 + 4 * c4);
    float4 bb = *(const float4*)(b2l + 4 * c4);
    for (int t = wv; t < NN / 8; t += nw) {
        int nA = t * 8 + 2 * g;
        float4 hA = *(const float4*)(H1 + (size_t)nA * HID + 4 * c4);
        float4 hB = *(const float4*)(H1 + (size_t)(nA + 1) * HID + 4 * c4);
        float4 aA, aB;
        aA.x = fmaxf(fmaf(hA.x, sc.x, sh.x), 0.f);
        aA.y = fmaxf(fmaf(hA.y, sc.y, sh.y), 0.f);
        aA.z = fmaxf(fmaf(hA.z, sc.z, sh.z), 0.f);
        aA.w = fmaxf(fmaf(hA.w, sc.w, sh.w), 0.f);
        aB.x = fmaxf(fmaf(hB.x, sc.x, sh.x), 0.f);
        aB.y = fmaxf(fmaf(hB.y, sc.y, sh.y), 0.f);
        aB.z = fmaxf(fmaf(hB.z, sc.z, sh.z), 0.f);
        aB.w = fmaxf(fmaf(hB.w, sc.w, sh.w), 0.f);
        float uA0 = 0, uA1 = 0, uA2 = 0, uA3 = 0, uB0 = 0, uB1 = 0, uB2 = 0, uB3 = 0;
        float zA0 = 0, zA1 = 0, zA2 = 0, zA3 = 0, zB0 = 0, zB1 = 0, zB2 = 0, zB3 = 0;
#pragma unroll
        for (int k = 0; k < HID; ++k) {
            int srcl = (g << 4) | (k >> 2);
            float cA = (k & 3) == 0 ? aA.x : (k & 3) == 1 ? aA.y : (k & 3) == 2 ? aA.z : aA.w;
            float cB = (k & 3) == 0 ? aB.x : (k & 3) == 1 ? aB.y : (k & 3) == 2 ? aB.z : aB.w;
            float vA = __shfl(cA, srcl);
            float vB = __shfl(cB, srcl);
            const float4 wl = *(const float4*)(ldsL + k * HID + 4 * c4);
            const float4 wr = *(const float4*)(ldsR + k * HID + 4 * c4);
            uA0 = fmaf(wl.x, vA, uA0); uA1 = fmaf(wl.y, vA, uA1);
            uA2 = fmaf(wl.z, vA, uA2); uA3 = fmaf(wl.w, vA, uA3);
            uB0 = fmaf(wl.x, vB, uB0); uB1 = fmaf(wl.y, vB, uB1);
            uB2 = fmaf(wl.z, vB, uB2); uB3 = fmaf(wl.w, vB, uB3);
            zA0 = fmaf(wr.x, vA, zA0); zA1 = fmaf(wr.y, vA, zA1);
            zA2 = fmaf(wr.z, vA, zA2); zA3 = fmaf(wr.w, vA, zA3);
            zB0 = fmaf(wr.x, vB, zB0); zB1 = fmaf(wr.y, vB, zB1);
            zB2 = fmaf(wr.z, vB, zB2); zB3 = fmaf(wr.w, vB, zB3);
        }
        float4 o;
        o.x = uA0; o.y = uA1; o.z = uA2; o.w = uA3;
        *(float4*)(U + (size_t)nA * HID + 4 * c4) = o;
        o.x = uB0; o.y = uB1; o.z = uB2; o.w = uB3;
        *(float4*)(U + (size_t)(nA + 1) * HID + 4 * c4) = o;
        o.x = zA0 + bb.x; o.y = zA1 + bb.y; o.z = zA2 + bb.z; o.w = zA3 + bb.w;
        *(float4*)(Z + (size_t)nA * HID + 4 * c4) = o;
        o.x = zB0 + bb.x; o.y = zB1 + bb.y; o.z = zB2 + bb.z; o.w = zB3 + bb.w;
        *(float4*)(Z + (size_t)(nA + 1) * HID + 4 * c4) = o;
    }
}

// ---------------- gather2: h2 = mean(U[src]) + Z  (in place over Z) ----------------

__global__ void __launch_bounds__(256, 8) kI_gather2(
    const float* __restrict__ U, const int* __restrict__ csr_src,
    const int* __restrict__ rowptr, float* __restrict__ ZH,
    float* __restrict__ gsum, float* __restrict__ gsq) {
    int lane = threadIdx.x & 63;
    int g = lane >> 4, c4 = lane & 15;
    int gw = blockIdx.x * 4 + (threadIdx.x >> 6);
    int nw = gridDim.x * 4;
    float ps0 = 0, ps1 = 0, ps2 = 0, ps3 = 0, pq0 = 0, pq1 = 0, pq2 = 0, pq3 = 0;

    for (int n = gw; n < NN; n += nw) {
        int beg = rowptr[n], end = rowptr[n + 1];
        float a0 = 0, a1 = 0, a2 = 0, a3 = 0;
        for (int p0 = beg; p0 < end; p0 += 64) {
            int cntj = min(64, end - p0);
            int sL = (lane < cntj) ? csr_src[p0 + lane] : 0;
            int jm = (cntj + 3) >> 2;
#pragma unroll 4
            for (int j = 0; j < jm; ++j) {
                int idx = j * 4 + g;
                int s = __shfl(sL, idx);
                float m = (idx < cntj) ? 1.f : 0.f;
                const float4 y = *(const float4*)(U + (size_t)s * HID + 4 * c4);
                a0 = fmaf(y.x, m, a0);
                a1 = fmaf(y.y, m, a1);
                a2 = fmaf(y.z, m, a2);
                a3 = fmaf(y.w, m, a3);
            }
        }
        GRED(a0) GRED(a1) GRED(a2) GRED(a3)
        if (g == 0) {
            float invd = 1.f / fmaxf((float)(end - beg), 1.f);
            float4 z = *(const float4*)(ZH + (size_t)n * HID + 4 * c4);
            float h0 = fmaf(a0, invd, z.x);
            float h1v = fmaf(a1, invd, z.y);
            float h2v = fmaf(a2, invd, z.z);
            float h3v = fmaf(a3, invd, z.w);
            float4 hv = {h0, h1v, h2v, h3v};
            *(float4*)(ZH + (size_t)n * HID + 4 * c4) = hv;
            ps0 += h0; ps1 += h1v; ps2 += h2v; ps3 += h3v;
            pq0 += h0 * h0; pq1 += h1v * h1v; pq2 += h2v * h2v; pq3 += h3v * h3v;
        }
    }
    __shared__ float bs[HID], bq[HID];
    if (threadIdx.x < HID) { bs[threadIdx.x] = 0.f; bq[threadIdx.x] = 0.f; }
    __syncthreads();
    if (g == 0) {
        atomicAdd(&bs[4 * c4 + 0], ps0); atomicAdd(&bq[4 * c4 + 0], pq0);
        atomicAdd(&bs[4 * c4 + 1], ps1); atomicAdd(&bq[4 * c4 + 1], pq1);
        atomicAdd(&bs[4 * c4 + 2], ps2); atomicAdd(&bq[4 * c4 + 2], pq2);
        atomicAdd(&bs[4 * c4 + 3], ps3); atomicAdd(&bq[4 * c4 + 3], pq3);
    }
    __syncthreads();
    if (threadIdx.x < HID) {
        atomicAdd(&gsum[threadIdx.x], bs[threadIdx.x]);
        atomicAdd(&gsq[threadIdx.x], bq[threadIdx.x]);
    }
}

// ---------------- output head ----------------

__global__ void kJ_out(const float* __restrict__ H2,
                       const float* __restrict__ sc2, const float* __restrict__ sh2,
                       const float* __restrict__ Wc, const float* __restrict__ bc,
                       float* __restrict__ out) {
    int lane = threadIdx.x & 63;
    int g = lane >> 4, c4 = lane & 15;
    int wv = blockIdx.x * 4 + (threadIdx.x >> 6);
    int nw = gridDim.x * 4;
    float4 sc = *(const float4*)(sc2 + 4 * c4);
    float4 sh = *(const float4*)(sh2 + 4 * c4);
    float4 w0 = *(const float4*)(Wc + 4 * c4);
    float4 w1 = *(const float4*)(Wc + HID + 4 * c4);
    float b0 = bc[0], b1 = bc[1];
    for (int t = wv; t < NN / 4; t += nw) {
        int n = t * 4 + g;
        float4 h = *(const float4*)(H2 + (size_t)n * HID + 4 * c4);
        float vx = fmaxf(fmaf(h.x, sc.x, sh.x), 0.f);
        float vy = fmaxf(fmaf(h.y, sc.y, sh.y), 0.f);
        float vz = fmaxf(fmaf(h.z, sc.z, sh.z), 0.f);
        float vw = fmaxf(fmaf(h.w, sc.w, sh.w), 0.f);
        float r0 = vx * w0.x + vy * w0.y + vz * w0.z + vw * w0.w;
        float r1 = vx * w1.x + vy * w1.y + vz * w1.z + vw * w1.w;
#pragma unroll
        for (int off = 1; off <= 8; off <<= 1) {
            r0 += __shfl_xor(r0, off);
            r1 += __shfl_xor(r1, off);
        }
        if (c4 == 0) {
            out[(size_t)n * 2] = r0 + b0;
            out[(size_t)n * 2 + 1] = r1 + b1;
        }
    }
}

// ---------------- host launcher ----------------

extern "C" void kernel_launch(void* const* d_in, const int* in_sizes, int n_in,
                              void* d_out, int out_size, void* d_ws, size_t ws_size,
                              hipStream_t stream) {
    const float* x = (const float*)d_in[0];
    const int* ei = (const int*)d_in[1];
    const float* eattr = (const float*)d_in[2];
    const float* We = (const float*)d_in[3];
    const float* be = (const float*)d_in[4];
    const float* W1l = (const float*)d_in[5];
    const float* b1l = (const float*)d_in[6];
    const float* W1r = (const float*)d_in[7];
    const float* W2l = (const float*)d_in[8];
    const float* b2l = (const float*)d_in[9];
    const float* W2r = (const float*)d_in[10];
    const float* g1 = (const float*)d_in[11];
    const float* beta1 = (const float*)d_in[12];
    const float* g2 = (const float*)d_in[13];
    const float* beta2 = (const float*)d_in[14];
    const float* Wc = (const float*)d_in[15];
    const float* bc = (const float*)d_in[16];
    float* out = (float*)d_out;

    const int* e_src = ei;
    const int* e_dst = ei + NE;

    char* ws = (char*)d_ws;
    size_t off = 0;
    auto alloc = [&](size_t b) {
        char* p = ws + off;
        off += (b + 255) & ~(size_t)255;
        return p;
    };
    int* rowptr = (int*)alloc((NN + 1) * sizeof(int));
    int* cnt = (int*)alloc(NN * sizeof(int));
    float4* pack = (float4*)alloc((size_t)NE * 16);                  // csr pack -> U after strip
    int* csr_src = (int*)alloc((size_t)NE * sizeof(int));            // slot -> stripped src
    float* bufY = (float*)alloc((size_t)NN * HID * sizeof(float));   // yl -> Z -> h2
    float* bufH = (float*)alloc((size_t)NN * HID * sizeof(float));   // own/H1
    float* stats = (float*)alloc(512 * sizeof(float));
    float* gsum1 = stats, *gsq1 = stats + 64, *gsum2 = stats + 128, *gsq2 = stats + 192;
    float* scale1 = stats + 256, *shift1 = stats + 320;
    float* scale2 = stats + 384, *shift2 = stats + 448;

    // liveness aliases:
    int* slot = csr_src;         // slot dead after kC_fill; csr_src born in kD_strip
    float* H1 = bufH;            // own -> h1 (dead after kH_pre2)
    float* U = (float*)pack;     // pack dead after kF_gather1+kD_strip; U born kH_pre2
    float* Z = bufY;             // yl dead after kF_gather1; h2 in place over Z

    hipMemsetAsync(cnt, 0, NN * sizeof(int), stream);
    hipMemsetAsync(stats, 0, 256 * sizeof(float), stream);

    kA_count<<<4096, 256, 0, stream>>>(e_dst, cnt, slot);
    kB_scan<<<1, 1024, 0, stream>>>(cnt, rowptr);
    kC_fill<<<4096, 256, 0, stream>>>(e_src, e_dst, eattr, rowptr, slot, pack);
    kE_pre1<<<2048, 256, 0, stream>>>(x, W1l, b1l, W1r, bufY, H1);
    kF_gather1<<<4096, 256, 0, stream>>>(bufY, pack, rowptr, We, be, H1, gsum1, gsq1);
    kD_strip<<<2048, 256, 0, stream>>>((const int4*)pack, csr_src);
    kG_bnstat<<<1, 64, 0, stream>>>(gsum1, gsq1, g1, beta1, scale1, shift1);
    kH_pre2<<<2048, 256, 0, stream>>>(H1, W2l, W2r, b2l, scale1, shift1, U, Z);
    kI_gather2<<<4096, 256, 0, stream>>>(U, csr_src, rowptr, Z, gsum2, gsq2);
    kG_bnstat<<<1, 64, 0, stream>>>(gsum2, gsq2, g2, beta2, scale2, shift2);
    kJ_out<<<512, 256, 0, stream>>>(Z, scale2, shift2, Wc, bc, out);
}

// Round 5
// 1234.545 us; speedup vs baseline: 1.0225x; 1.0225x over previous
//
#include <hip/hip_runtime.h>

#define NN 100000
#define NE 3200000
#define F_IN 21
#define HID 64
#define EPS 1e-5f

// ---------------- CSR build ----------------

__global__ void kA_count_r5(const int* __restrict__ dst, int* __restrict__ cnt,
                            int* __restrict__ slot) {
    int i = blockIdx.x * blockDim.x + threadIdx.x;
    int st = gridDim.x * blockDim.x;
    for (int e = i; e < NE; e += st) slot[e] = atomicAdd(&cnt[dst[e]], 1);
}

__global__ void kB_scan_r5(const int* __restrict__ cnt, int* __restrict__ rowptr) {
    __shared__ int lds[1024];
    int t = threadIdx.x;
    const int CH = 100;
    int lo = t * CH;
    int s = 0;
    if (lo < NN) {
        const int4* p = (const int4*)(cnt + lo);
#pragma unroll
        for (int i = 0; i < CH / 4; ++i) { int4 v = p[i]; s += v.x + v.y + v.z + v.w; }
    }
    lds[t] = s;
    __syncthreads();
    for (int off = 1; off < 1024; off <<= 1) {
        int v = (t >= off) ? lds[t - off] : 0;
        __syncthreads();
        lds[t] += v;
        __syncthreads();
    }
    if (lo < NN) {
        int run = lds[t] - s;
        for (int i = lo; i < lo + CH; ++i) { rowptr[i] = run; run += cnt[i]; }
    }
    if (t == 0) rowptr[NN] = NE;
}

// one 16B aligned scatter per edge: {src_bits, a0, a1, a2}
__global__ void kC_fill_r5(const int* __restrict__ src, const int* __restrict__ dst,
                           const float* __restrict__ eattr,
                           const int* __restrict__ rowptr, const int* __restrict__ slot,
                           float4* __restrict__ pack) {
    int i = blockIdx.x * blockDim.x + threadIdx.x;
    int st = gridDim.x * blockDim.x;
    for (int e = i; e < NE; e += st) {
        int d = dst[e];
        int pos = rowptr[d] + slot[e];
        size_t eb = (size_t)e * 3;
        float4 pk;
        pk.x = __int_as_float(src[e]);
        pk.y = eattr[eb];
        pk.z = eattr[eb + 1];
        pk.w = eattr[eb + 2];
        pack[pos] = pk;
    }
}

// pad x [N,21] -> xp [N,32] (zero-padded) for 8-lane float4 group gathers
__global__ void kP_pad_r5(const float* __restrict__ x, float* __restrict__ xp) {
    int i = blockIdx.x * blockDim.x + threadIdx.x;
    int st = gridDim.x * blockDim.x;
    for (; i < NN * 32; i += st) {
        int n = i >> 5, c = i & 31;
        xp[i] = (c < F_IN) ? x[(size_t)n * F_IN + c] : 0.f;
    }
}

// coalesced extraction of csr_src from the pack (runs after gather1; writes over xp)
__global__ void kD_strip_r5(const int4* __restrict__ pack, int* __restrict__ csr_src) {
    int i = blockIdx.x * blockDim.x + threadIdx.x;
    int st = gridDim.x * blockDim.x;
    for (int e = i; e < NE; e += st) csr_src[e] = pack[e].x;
}

// ---------------- gather1: ax[n]=sum x[src]; H1[n]=sum relu(We@attr+be) --------
// wave per node; 8 groups x 8 lanes; lane q holds x-quad q and e-channels 8q..8q+7

#define R3X(v) { v += __shfl_xor(v, 8); v += __shfl_xor(v, 16); v += __shfl_xor(v, 32); }
#define R2X(v) { v += __shfl_xor(v, 16); v += __shfl_xor(v, 32); }

__global__ void __launch_bounds__(256, 4) kG1_gather_r5(
    const float4* __restrict__ pack, const float4* __restrict__ xp4,
    const int* __restrict__ rowptr,
    const float* __restrict__ We, const float* __restrict__ be,
    float* __restrict__ H1, float4* __restrict__ ax4) {
    int lane = threadIdx.x & 63;
    int g = lane >> 3, q = lane & 7;
    float w0[8], w1[8], w2[8], bb[8];
#pragma unroll
    for (int r = 0; r < 8; ++r) {
        int ch = 8 * q + r;
        w0[r] = We[ch * 3]; w1[r] = We[ch * 3 + 1]; w2[r] = We[ch * 3 + 2];
        bb[r] = be[ch];
    }
    int gw = blockIdx.x * 4 + (threadIdx.x >> 6);
    int nw = gridDim.x * 4;
    for (int n = gw; n < NN; n += nw) {
        int beg = rowptr[n], end = rowptr[n + 1];
        float aX0 = 0, aX1 = 0, aX2 = 0, aX3 = 0;
        float aE[8] = {0, 0, 0, 0, 0, 0, 0, 0};
        for (int p = beg + g; p < end; p += 8) {
            float4 pk = pack[p];                         // 8-lane same-line broadcast
            int s = __float_as_int(pk.x);
            float4 xv = xp4[(size_t)s * 8 + q];          // 128B row per edge
            aX0 += xv.x; aX1 += xv.y; aX2 += xv.z; aX3 += xv.w;
#pragma unroll
            for (int r = 0; r < 8; ++r) {
                float e = fmaf(w0[r], pk.y, fmaf(w1[r], pk.z, fmaf(w2[r], pk.w, bb[r])));
                aE[r] += fmaxf(e, 0.f);
            }
        }
        R3X(aX0) R3X(aX1) R3X(aX2) R3X(aX3)
#pragma unroll
        for (int r = 0; r < 8; ++r) { R3X(aE[r]) }
        if (g == 0) {
            float4 xq = {aX0, aX1, aX2, aX3};
            ax4[(size_t)n * 8 + q] = xq;
            float4 e0 = {aE[0], aE[1], aE[2], aE[3]};
            float4 e1 = {aE[4], aE[5], aE[6], aE[7]};
            *(float4*)(H1 + (size_t)n * HID + 8 * q) = e0;
            *(float4*)(H1 + (size_t)n * HID + 8 * q + 4) = e1;
        }
    }
}

// ---------------- post1: h1 = x@W1r.T + b1 + (ax/deg)@W1l.T + H1(eagg); BN1 stats --

__global__ void __launch_bounds__(256, 4) kQ1_post_r5(
    const float* __restrict__ x, const float* __restrict__ ax,
    const float* __restrict__ W1l, const float* __restrict__ b1l,
    const float* __restrict__ W1r, const int* __restrict__ rowptr,
    float* __restrict__ H1, float* __restrict__ gsum, float* __restrict__ gsq) {
    int lane = threadIdx.x & 63;
    float wl[F_IN], wr[F_IN];
#pragma unroll
    for (int k = 0; k < F_IN; ++k) {
        wl[k] = W1l[lane * F_IN + k];
        wr[k] = W1r[lane * F_IN + k];
    }
    float b = b1l[lane];
    int gw = blockIdx.x * 4 + (threadIdx.x >> 6);
    int nw = gridDim.x * 4;
    float psum = 0.f, psq = 0.f;
    for (int n = gw; n < NN; n += nw) {
        float xv = (lane < F_IN) ? x[(size_t)n * F_IN + lane] : 0.f;
        float av = (lane < 32) ? ax[(size_t)n * 32 + lane] : 0.f;
        float own = b, agg = 0.f;
#pragma unroll
        for (int k = 0; k < F_IN; ++k) {
            own = fmaf(wr[k], __shfl(xv, k), own);
            agg = fmaf(wl[k], __shfl(av, k), agg);
        }
        int deg = rowptr[n + 1] - rowptr[n];
        float invd = 1.f / fmaxf((float)deg, 1.f);
        float h = own + agg * invd + H1[(size_t)n * HID + lane];
        H1[(size_t)n * HID + lane] = h;
        psum += h; psq += h * h;
    }
    __shared__ float bs[HID], bq[HID];
    if (threadIdx.x < HID) { bs[threadIdx.x] = 0.f; bq[threadIdx.x] = 0.f; }
    __syncthreads();
    atomicAdd(&bs[lane], psum);
    atomicAdd(&bq[lane], psq);
    __syncthreads();
    if (threadIdx.x < HID) {
        atomicAdd(&gsum[threadIdx.x], bs[threadIdx.x]);
        atomicAdd(&gsq[threadIdx.x], bq[threadIdx.x]);
    }
}

// ---------------- BN finalize ----------------

__global__ void kG_bnstat_r5(const float* __restrict__ gsum, const float* __restrict__ gsq,
                             const float* __restrict__ g, const float* __restrict__ beta,
                             float* __restrict__ scale, float* __restrict__ shift) {
    int c = threadIdx.x;
    if (c < HID) {
        float mu = gsum[c] * (1.f / (float)NN);
        float var = gsq[c] * (1.f / (float)NN) - mu * mu;
        float rstd = rsqrtf(var + EPS);
        float sc = rstd * g[c];
        scale[c] = sc;
        shift[c] = beta[c] - mu * sc;
    }
}

// ---------------- gather2: agg2[n] = sum relu(bn(h1[src])) ----------------
// wave per node; 4 groups x 16 lanes; bn+relu fused into the gather

__global__ void __launch_bounds__(256, 8) kG2_gather_r5(
    const float* __restrict__ H1, const int* __restrict__ csr_src,
    const int* __restrict__ rowptr,
    const float* __restrict__ sc1, const float* __restrict__ sh1,
    float* __restrict__ agg2) {
    int lane = threadIdx.x & 63;
    int g = lane >> 4, c4 = lane & 15;
    float4 sc = *(const float4*)(sc1 + 4 * c4);
    float4 sh = *(const float4*)(sh1 + 4 * c4);
    int gw = blockIdx.x * 4 + (threadIdx.x >> 6);
    int nw = gridDim.x * 4;
    for (int n = gw; n < NN; n += nw) {
        int beg = rowptr[n], end = rowptr[n + 1];
        float a0 = 0, a1 = 0, a2 = 0, a3 = 0;
        for (int p = beg + g; p < end; p += 4) {
            int s = csr_src[p];                          // 16-lane same-line broadcast
            const float4 y = *(const float4*)(H1 + (size_t)s * HID + 4 * c4);
            a0 += fmaxf(fmaf(y.x, sc.x, sh.x), 0.f);
            a1 += fmaxf(fmaf(y.y, sc.y, sh.y), 0.f);
            a2 += fmaxf(fmaf(y.z, sc.z, sh.z), 0.f);
            a3 += fmaxf(fmaf(y.w, sc.w, sh.w), 0.f);
        }
        R2X(a0) R2X(a1) R2X(a2) R2X(a3)
        if (g == 0) {
            float4 o = {a0, a1, a2, a3};
            *(float4*)(agg2 + (size_t)n * HID + 4 * c4) = o;
        }
    }
}

// ---------------- post2: h2 = (agg2/deg)@W2l.T + relu(bn(h1))@W2r.T + b2; BN2 ----
// 4 groups x 2 nodes = 8 nodes per wave-tile; weights transposed in LDS

#define PICK(v, kk) ((kk) == 0 ? (v).x : (kk) == 1 ? (v).y : (kk) == 2 ? (v).z : (v).w)

__global__ void __launch_bounds__(256, 4) kQ2_post_r5(
    const float* __restrict__ H1, const float* __restrict__ agg2,
    const int* __restrict__ rowptr,
    const float* __restrict__ W2l, const float* __restrict__ W2r,
    const float* __restrict__ b2l,
    const float* __restrict__ sc1, const float* __restrict__ sh1,
    float* __restrict__ h2, float* __restrict__ gsum, float* __restrict__ gsq) {
    __shared__ float ldsL[HID * HID];  // [k][c]
    __shared__ float ldsR[HID * HID];
    for (int i = threadIdx.x; i < HID * HID; i += blockDim.x) {
        int k = i >> 6, c = i & 63;
        ldsL[i] = W2l[c * HID + k];
        ldsR[i] = W2r[c * HID + k];
    }
    __syncthreads();
    int lane = threadIdx.x & 63;
    int g = lane >> 4, c4 = lane & 15;
    float4 sc = *(const float4*)(sc1 + 4 * c4);
    float4 sh = *(const float4*)(sh1 + 4 * c4);
    float4 bb = *(const float4*)(b2l + 4 * c4);
    int wv = blockIdx.x * 4 + (threadIdx.x >> 6);
    int nw = gridDim.x * 4;
    float ps0 = 0, ps1 = 0, ps2 = 0, ps3 = 0, pq0 = 0, pq1 = 0, pq2 = 0, pq3 = 0;
    for (int t = wv; t < NN / 8; t += nw) {
        int nA = t * 8 + 2 * g;
        int r0 = rowptr[nA], r1 = rowptr[nA + 1], r2 = rowptr[nA + 2];
        float invA = 1.f / fmaxf((float)(r1 - r0), 1.f);
        float invB = 1.f / fmaxf((float)(r2 - r1), 1.f);
        float4 gA = *(const float4*)(agg2 + (size_t)nA * HID + 4 * c4);
        float4 gB = *(const float4*)(agg2 + (size_t)(nA + 1) * HID + 4 * c4);
        float4 hA = *(const float4*)(H1 + (size_t)nA * HID + 4 * c4);
        float4 hB = *(const float4*)(H1 + (size_t)(nA + 1) * HID + 4 * c4);
        float4 v1A = {gA.x * invA, gA.y * invA, gA.z * invA, gA.w * invA};
        float4 v1B = {gB.x * invB, gB.y * invB, gB.z * invB, gB.w * invB};
        float4 v2A, v2B;
        v2A.x = fmaxf(fmaf(hA.x, sc.x, sh.x), 0.f);
        v2A.y = fmaxf(fmaf(hA.y, sc.y, sh.y), 0.f);
        v2A.z = fmaxf(fmaf(hA.z, sc.z, sh.z), 0.f);
        v2A.w = fmaxf(fmaf(hA.w, sc.w, sh.w), 0.f);
        v2B.x = fmaxf(fmaf(hB.x, sc.x, sh.x), 0.f);
        v2B.y = fmaxf(fmaf(hB.y, sc.y, sh.y), 0.f);
        v2B.z = fmaxf(fmaf(hB.z, sc.z, sh.z), 0.f);
        v2B.w = fmaxf(fmaf(hB.w, sc.w, sh.w), 0.f);
        float oA0 = 0, oA1 = 0, oA2 = 0, oA3 = 0;
        float oB0 = 0, oB1 = 0, oB2 = 0, oB3 = 0;
#pragma unroll
        for (int k = 0; k < HID; ++k) {
            int srcl = (g << 4) | (k >> 2);
            float a1v = __shfl(PICK(v1A, k & 3), srcl);
            float a2v = __shfl(PICK(v2A, k & 3), srcl);
            float b1v = __shfl(PICK(v1B, k & 3), srcl);
            float b2v = __shfl(PICK(v2B, k & 3), srcl);
            const float4 wl = *(const float4*)(ldsL + k * HID + 4 * c4);
            const float4 wr = *(const float4*)(ldsR + k * HID + 4 * c4);
            oA0 = fmaf(wl.x, a1v, fmaf(wr.x, a2v, oA0));
            oA1 = fmaf(wl.y, a1v, fmaf(wr.y, a2v, oA1));
            oA2 = fmaf(wl.z, a1v, fmaf(wr.z, a2v, oA2));
            oA3 = fmaf(wl.w, a1v, fmaf(wr.w, a2v, oA3));
            oB0 = fmaf(wl.x, b1v, fmaf(wr.x, b2v, oB0));
            oB1 = fmaf(wl.y, b1v, fmaf(wr.y, b2v, oB1));
            oB2 = fmaf(wl.z, b1v, fmaf(wr.z, b2v, oB2));
            oB3 = fmaf(wl.w, b1v, fmaf(wr.w, b2v, oB3));
        }
        oA0 += bb.x; oA1 += bb.y; oA2 += bb.z; oA3 += bb.w;
        oB0 += bb.x; oB1 += bb.y; oB2 += bb.z; oB3 += bb.w;
        float4 oA = {oA0, oA1, oA2, oA3};
        float4 oB = {oB0, oB1, oB2, oB3};
        *(float4*)(h2 + (size_t)nA * HID + 4 * c4) = oA;
        *(float4*)(h2 + (size_t)(nA + 1) * HID + 4 * c4) = oB;
        ps0 += oA0 + oB0; ps1 += oA1 + oB1; ps2 += oA2 + oB2; ps3 += oA3 + oB3;
        pq0 += oA0 * oA0 + oB0 * oB0; pq1 += oA1 * oA1 + oB1 * oB1;
        pq2 += oA2 * oA2 + oB2 * oB2; pq3 += oA3 * oA3 + oB3 * oB3;
    }
    __shared__ float bs[HID], bq[HID];
    if (threadIdx.x < HID) { bs[threadIdx.x] = 0.f; bq[threadIdx.x] = 0.f; }
    __syncthreads();
    atomicAdd(&bs[4 * c4 + 0], ps0); atomicAdd(&bq[4 * c4 + 0], pq0);
    atomicAdd(&bs[4 * c4 + 1], ps1); atomicAdd(&bq[4 * c4 + 1], pq1);
    atomicAdd(&bs[4 * c4 + 2], ps2); atomicAdd(&bq[4 * c4 + 2], pq2);
    atomicAdd(&bs[4 * c4 + 3], ps3); atomicAdd(&bq[4 * c4 + 3], pq3);
    __syncthreads();
    if (threadIdx.x < HID) {
        atomicAdd(&gsum[threadIdx.x], bs[threadIdx.x]);
        atomicAdd(&gsq[threadIdx.x], bq[threadIdx.x]);
    }
}

// ---------------- output head ----------------

__global__ void kJ_out_r5(const float* __restrict__ H2,
                          const float* __restrict__ sc2, const float* __restrict__ sh2,
                          const float* __restrict__ Wc, const float* __restrict__ bc,
                          float* __restrict__ out) {
    int lane = threadIdx.x & 63;
    int g = lane >> 4, c4 = lane & 15;
    int wv = blockIdx.x * 4 + (threadIdx.x >> 6);
    int nw = gridDim.x * 4;
    float4 sc = *(const float4*)(sc2 + 4 * c4);
    float4 sh = *(const float4*)(sh2 + 4 * c4);
    float4 w0 = *(const float4*)(Wc + 4 * c4);
    float4 w1 = *(const float4*)(Wc + HID + 4 * c4);
    float b0 = bc[0], b1 = bc[1];
    for (int t = wv; t < NN / 4; t += nw) {
        int n = t * 4 + g;
        float4 h = *(const float4*)(H2 + (size_t)n * HID + 4 * c4);
        float vx = fmaxf(fmaf(h.x, sc.x, sh.x), 0.f);
        float vy = fmaxf(fmaf(h.y, sc.y, sh.y), 0.f);
        float vz = fmaxf(fmaf(h.z, sc.z, sh.z), 0.f);
        float vw = fmaxf(fmaf(h.w, sc.w, sh.w), 0.f);
        float r0 = vx * w0.x + vy * w0.y + vz * w0.z + vw * w0.w;
        float r1 = vx * w1.x + vy * w1.y + vz * w1.z + vw * w1.w;
#pragma unroll
        for (int off = 1; off <= 8; off <<= 1) {
            r0 += __shfl_xor(r0, off);
            r1 += __shfl_xor(r1, off);
        }
        if (c4 == 0) {
            out[(size_t)n * 2] = r0 + b0;
            out[(size_t)n * 2 + 1] = r1 + b1;
        }
    }
}

// ---------------- host launcher ----------------

extern "C" void kernel_launch(void* const* d_in, const int* in_sizes, int n_in,
                              void* d_out, int out_size, void* d_ws, size_t ws_size,
                              hipStream_t stream) {
    const float* x = (const float*)d_in[0];
    const int* ei = (const int*)d_in[1];
    const float* eattr = (const float*)d_in[2];
    const float* We = (const float*)d_in[3];
    const float* be = (const float*)d_in[4];
    const float* W1l = (const float*)d_in[5];
    const float* b1l = (const float*)d_in[6];
    const float* W1r = (const float*)d_in[7];
    const float* W2l = (const float*)d_in[8];
    const float* b2l = (const float*)d_in[9];
    const float* W2r = (const float*)d_in[10];
    const float* g1 = (const float*)d_in[11];
    const float* beta1 = (const float*)d_in[12];
    const float* g2 = (const float*)d_in[13];
    const float* beta2 = (const float*)d_in[14];
    const float* Wc = (const float*)d_in[15];
    const float* bc = (const float*)d_in[16];
    float* out = (float*)d_out;

    const int* e_src = ei;
    const int* e_dst = ei + NE;

    char* ws = (char*)d_ws;
    size_t off = 0;
    auto alloc = [&](size_t b) {
        char* p = ws + off;
        off += (b + 255) & ~(size_t)255;
        return p;
    };
    int* rowptr = (int*)alloc((NN + 1) * sizeof(int));
    int* cnt = (int*)alloc(NN * sizeof(int));
    float4* pack = (float4*)alloc((size_t)NE * 16);        // 51.2MB: pack -> agg2(front)+h2(back)
    char* bufD = alloc((size_t)NE * sizeof(int));          // 12.8MB: slot -> xp -> csr_src
    float* ax = (float*)alloc((size_t)NN * 32 * sizeof(float));  // 12.8MB
    float* H1 = (float*)alloc((size_t)NN * HID * sizeof(float)); // 25.6MB: eagg -> h1
    float* stats = (float*)alloc(512 * sizeof(float));
    float* gsum1 = stats, *gsq1 = stats + 64, *gsum2 = stats + 128, *gsq2 = stats + 192;
    float* scale1 = stats + 256, *shift1 = stats + 320;
    float* scale2 = stats + 384, *shift2 = stats + 448;

    int* slot = (int*)bufD;        // live kA -> kC
    float* xp = (float*)bufD;      // live kP -> kG1
    int* csr_src = (int*)bufD;     // live kD -> kG2
    float* agg2 = (float*)pack;                               // front 25.6MB, live kG2 -> kQ2
    float* h2 = (float*)((char*)pack + (size_t)NN * HID * 4); // back 25.6MB, live kQ2 -> kJ

    hipMemsetAsync(cnt, 0, NN * sizeof(int), stream);
    hipMemsetAsync(stats, 0, 256 * sizeof(float), stream);

    kA_count_r5<<<2048, 256, 0, stream>>>(e_dst, cnt, slot);
    kB_scan_r5<<<1, 1024, 0, stream>>>(cnt, rowptr);
    kC_fill_r5<<<2048, 256, 0, stream>>>(e_src, e_dst, eattr, rowptr, slot, pack);
    kP_pad_r5<<<1024, 256, 0, stream>>>(x, xp);
    kG1_gather_r5<<<2048, 256, 0, stream>>>(pack, (const float4*)xp, rowptr, We, be,
                                            H1, (float4*)ax);
    kD_strip_r5<<<2048, 256, 0, stream>>>((const int4*)pack, csr_src);
    kQ1_post_r5<<<2048, 256, 0, stream>>>(x, ax, W1l, b1l, W1r, rowptr, H1, gsum1, gsq1);
    kG_bnstat_r5<<<1, 64, 0, stream>>>(gsum1, gsq1, g1, beta1, scale1, shift1);
    kG2_gather_r5<<<4096, 256, 0, stream>>>(H1, csr_src, rowptr, scale1, shift1, agg2);
    kQ2_post_r5<<<2048, 256, 0, stream>>>(H1, agg2, rowptr, W2l, W2r, b2l,
                                          scale1, shift1, h2, gsum2, gsq2);
    kG_bnstat_r5<<<1, 64, 0, stream>>>(gsum2, gsq2, g2, beta2, scale2, shift2);
    kJ_out_r5<<<512, 256, 0, stream>>>(h2, scale2, shift2, Wc, bc, out);
}

// Round 6
// 1212.270 us; speedup vs baseline: 1.0413x; 1.0184x over previous
//
#include <hip/hip_runtime.h>

#define NN 100000
#define NE 3200000
#define F_IN 21
#define HID 64
#define EPS 1e-5f

// ---------------- CSR build ----------------

__global__ void kA_count_r6(const int* __restrict__ dst, int* __restrict__ cnt,
                            int* __restrict__ slot) {
    int i = blockIdx.x * blockDim.x + threadIdx.x;
    int st = gridDim.x * blockDim.x;
    for (int e = i; e < NE; e += st) slot[e] = atomicAdd(&cnt[dst[e]], 1);
}

__global__ void kB_scan_r6(const int* __restrict__ cnt, int* __restrict__ rowptr) {
    __shared__ int lds[1024];
    int t = threadIdx.x;
    const int CH = 100;
    int lo = t * CH;
    int s = 0;
    if (lo < NN) {
        const int4* p = (const int4*)(cnt + lo);
#pragma unroll
        for (int i = 0; i < CH / 4; ++i) { int4 v = p[i]; s += v.x + v.y + v.z + v.w; }
    }
    lds[t] = s;
    __syncthreads();
    for (int off = 1; off < 1024; off <<= 1) {
        int v = (t >= off) ? lds[t - off] : 0;
        __syncthreads();
        lds[t] += v;
        __syncthreads();
    }
    if (lo < NN) {
        int run = lds[t] - s;
        for (int i = lo; i < lo + CH; ++i) { rowptr[i] = run; run += cnt[i]; }
    }
    if (t == 0) rowptr[NN] = NE;
}

// one 16B aligned scatter per edge: {src_bits, a0, a1, a2}
__global__ void kC_fill_r6(const int* __restrict__ src, const int* __restrict__ dst,
                           const float* __restrict__ eattr,
                           const int* __restrict__ rowptr, const int* __restrict__ slot,
                           float4* __restrict__ pack) {
    int i = blockIdx.x * blockDim.x + threadIdx.x;
    int st = gridDim.x * blockDim.x;
    for (int e = i; e < NE; e += st) {
        int d = dst[e];
        int pos = rowptr[d] + slot[e];
        size_t eb = (size_t)e * 3;
        float4 pk;
        pk.x = __int_as_float(src[e]);
        pk.y = eattr[eb];
        pk.z = eattr[eb + 1];
        pk.w = eattr[eb + 2];
        pack[pos] = pk;
    }
}

// pad x [N,21] -> xp [N,32] (zero-padded)
__global__ void kP_pad_r6(const float* __restrict__ x, float* __restrict__ xp) {
    int i = blockIdx.x * blockDim.x + threadIdx.x;
    int st = gridDim.x * blockDim.x;
    for (; i < NN * 32; i += st) {
        int n = i >> 5, c = i & 31;
        xp[i] = (c < F_IN) ? x[(size_t)n * F_IN + c] : 0.f;
    }
}

// coalesced extraction of csr_src from the pack
__global__ void kD_strip_r6(const int4* __restrict__ pack, int* __restrict__ csr_src) {
    int i = blockIdx.x * blockDim.x + threadIdx.x;
    int st = gridDim.x * blockDim.x;
    for (int e = i; e < NE; e += st) csr_src[e] = pack[e].x;
}

// ---------------- gather1: ax[n]=sum x[src]; H1[n]=sum relu(We@attr+be) --------
// wave per node; 8 groups x 8 lanes; stage 64 edges in regs, unrolled 4-deep loads

#define R3X(v) { v += __shfl_xor(v, 8); v += __shfl_xor(v, 16); v += __shfl_xor(v, 32); }
#define R2X(v) { v += __shfl_xor(v, 16); v += __shfl_xor(v, 32); }

__global__ void __launch_bounds__(256, 4) kG1_gather_r6(
    const float4* __restrict__ pack, const float4* __restrict__ xp4,
    const int* __restrict__ rowptr,
    const float* __restrict__ We, const float* __restrict__ be,
    float* __restrict__ H1, float4* __restrict__ ax4) {
    int lane = threadIdx.x & 63;
    int g = lane >> 3, q = lane & 7;
    float w0[8], w1[8], w2[8], bb[8];
#pragma unroll
    for (int r = 0; r < 8; ++r) {
        int ch = 8 * q + r;
        w0[r] = We[ch * 3]; w1[r] = We[ch * 3 + 1]; w2[r] = We[ch * 3 + 2];
        bb[r] = be[ch];
    }
    int gw = blockIdx.x * 4 + (threadIdx.x >> 6);
    int nw = gridDim.x * 4;
    for (int n = gw; n < NN; n += nw) {
        int beg = rowptr[n], end = rowptr[n + 1];
        float aX0 = 0, aX1 = 0, aX2 = 0, aX3 = 0;
        float aE[8] = {0, 0, 0, 0, 0, 0, 0, 0};
        for (int p0 = beg; p0 < end; p0 += 64) {
            int cnt = min(64, end - p0);
            float4 pkL = {0.f, 0.f, 0.f, 0.f};
            if (lane < cnt) pkL = pack[p0 + lane];   // 64 edges staged, coalesced 1KB
            int jm = (cnt + 7) >> 3;
#pragma unroll 4
            for (int j = 0; j < jm; ++j) {
                int idx = j * 8 + g;
                int s = __float_as_int(__shfl(pkL.x, idx));
                float a0 = __shfl(pkL.y, idx);
                float a1 = __shfl(pkL.z, idx);
                float a2 = __shfl(pkL.w, idx);
                float m = (idx < cnt) ? 1.f : 0.f;
                float4 xv = xp4[(size_t)s * 8 + q];  // independent 128B row loads
                aX0 = fmaf(xv.x, m, aX0);
                aX1 = fmaf(xv.y, m, aX1);
                aX2 = fmaf(xv.z, m, aX2);
                aX3 = fmaf(xv.w, m, aX3);
#pragma unroll
                for (int r = 0; r < 8; ++r) {
                    float e = fmaf(w0[r], a0, fmaf(w1[r], a1, fmaf(w2[r], a2, bb[r])));
                    aE[r] = fmaf(fmaxf(e, 0.f), m, aE[r]);
                }
            }
        }
        R3X(aX0) R3X(aX1) R3X(aX2) R3X(aX3)
#pragma unroll
        for (int r = 0; r < 8; ++r) { R3X(aE[r]) }
        if (g == 0) {
            float4 xq = {aX0, aX1, aX2, aX3};
            ax4[(size_t)n * 8 + q] = xq;
            float4 e0 = {aE[0], aE[1], aE[2], aE[3]};
            float4 e1 = {aE[4], aE[5], aE[6], aE[7]};
            *(float4*)(H1 + (size_t)n * HID + 8 * q) = e0;
            *(float4*)(H1 + (size_t)n * HID + 8 * q + 4) = e1;
        }
    }
}

// ---------------- post1: h1 = x@W1r.T + b1 + (ax/deg)@W1l.T + H1(eagg); BN1 stats --

__global__ void __launch_bounds__(256, 4) kQ1_post_r6(
    const float* __restrict__ x, const float* __restrict__ ax,
    const float* __restrict__ W1l, const float* __restrict__ b1l,
    const float* __restrict__ W1r, const int* __restrict__ rowptr,
    float* __restrict__ H1, float* __restrict__ gsum, float* __restrict__ gsq) {
    int lane = threadIdx.x & 63;
    float wl[F_IN], wr[F_IN];
#pragma unroll
    for (int k = 0; k < F_IN; ++k) {
        wl[k] = W1l[lane * F_IN + k];
        wr[k] = W1r[lane * F_IN + k];
    }
    float b = b1l[lane];
    int gw = blockIdx.x * 4 + (threadIdx.x >> 6);
    int nw = gridDim.x * 4;
    float psum = 0.f, psq = 0.f;
    for (int n = gw; n < NN; n += nw) {
        float xv = (lane < F_IN) ? x[(size_t)n * F_IN + lane] : 0.f;
        float av = (lane < 32) ? ax[(size_t)n * 32 + lane] : 0.f;
        float own = b, agg = 0.f;
#pragma unroll
        for (int k = 0; k < F_IN; ++k) {
            own = fmaf(wr[k], __shfl(xv, k), own);
            agg = fmaf(wl[k], __shfl(av, k), agg);
        }
        int deg = rowptr[n + 1] - rowptr[n];
        float invd = 1.f / fmaxf((float)deg, 1.f);
        float h = own + agg * invd + H1[(size_t)n * HID + lane];
        H1[(size_t)n * HID + lane] = h;
        psum += h; psq += h * h;
    }
    __shared__ float bs[HID], bq[HID];
    if (threadIdx.x < HID) { bs[threadIdx.x] = 0.f; bq[threadIdx.x] = 0.f; }
    __syncthreads();
    atomicAdd(&bs[lane], psum);
    atomicAdd(&bq[lane], psq);
    __syncthreads();
    if (threadIdx.x < HID) {
        atomicAdd(&gsum[threadIdx.x], bs[threadIdx.x]);
        atomicAdd(&gsq[threadIdx.x], bq[threadIdx.x]);
    }
}

// ---------------- BN finalize ----------------

__global__ void kG_bnstat_r6(const float* __restrict__ gsum, const float* __restrict__ gsq,
                             const float* __restrict__ g, const float* __restrict__ beta,
                             float* __restrict__ scale, float* __restrict__ shift) {
    int c = threadIdx.x;
    if (c < HID) {
        float mu = gsum[c] * (1.f / (float)NN);
        float var = gsq[c] * (1.f / (float)NN) - mu * mu;
        float rstd = rsqrtf(var + EPS);
        float sc = rstd * g[c];
        scale[c] = sc;
        shift[c] = beta[c] - mu * sc;
    }
}

// ---------------- gather2: agg2[n] = sum relu(bn(h1[src])) ----------------
// wave per node; 4 groups x 16 lanes; stage 64 indices, unrolled 8-deep row loads

__global__ void __launch_bounds__(256, 4) kG2_gather_r6(
    const float* __restrict__ H1, const int* __restrict__ csr_src,
    const int* __restrict__ rowptr,
    const float* __restrict__ sc1, const float* __restrict__ sh1,
    float* __restrict__ agg2) {
    int lane = threadIdx.x & 63;
    int g = lane >> 4, c4 = lane & 15;
    float4 sc = *(const float4*)(sc1 + 4 * c4);
    float4 sh = *(const float4*)(sh1 + 4 * c4);
    int gw = blockIdx.x * 4 + (threadIdx.x >> 6);
    int nw = gridDim.x * 4;
    for (int n = gw; n < NN; n += nw) {
        int beg = rowptr[n], end = rowptr[n + 1];
        float a0 = 0, a1 = 0, a2 = 0, a3 = 0;
        for (int p0 = beg; p0 < end; p0 += 64) {
            int cnt = min(64, end - p0);
            int sL = (lane < cnt) ? csr_src[p0 + lane] : 0;  // 64 indices staged
            int jm = (cnt + 3) >> 2;
#pragma unroll 8
            for (int j = 0; j < jm; ++j) {
                int idx = j * 4 + g;
                int s = __shfl(sL, idx);
                float m = (idx < cnt) ? 1.f : 0.f;
                const float4 y = *(const float4*)(H1 + (size_t)s * HID + 4 * c4);
                a0 += fmaxf(fmaf(y.x, sc.x, sh.x), 0.f) * m;
                a1 += fmaxf(fmaf(y.y, sc.y, sh.y), 0.f) * m;
                a2 += fmaxf(fmaf(y.z, sc.z, sh.z), 0.f) * m;
                a3 += fmaxf(fmaf(y.w, sc.w, sh.w), 0.f) * m;
            }
        }
        R2X(a0) R2X(a1) R2X(a2) R2X(a3)
        if (g == 0) {
            float4 o = {a0, a1, a2, a3};
            *(float4*)(agg2 + (size_t)n * HID + 4 * c4) = o;
        }
    }
}

// ---------------- post2: h2 = (agg2/deg)@W2l.T + relu(bn(h1))@W2r.T + b2; BN2 ----

#define PICK(v, kk) ((kk) == 0 ? (v).x : (kk) == 1 ? (v).y : (kk) == 2 ? (v).z : (v).w)

__global__ void __launch_bounds__(256, 4) kQ2_post_r6(
    const float* __restrict__ H1, const float* __restrict__ agg2,
    const int* __restrict__ rowptr,
    const float* __restrict__ W2l, const float* __restrict__ W2r,
    const float* __restrict__ b2l,
    const float* __restrict__ sc1, const float* __restrict__ sh1,
    float* __restrict__ h2, float* __restrict__ gsum, float* __restrict__ gsq) {
    __shared__ float ldsL[HID * HID];  // [k][c]
    __shared__ float ldsR[HID * HID];
    for (int i = threadIdx.x; i < HID * HID; i += blockDim.x) {
        int k = i >> 6, c = i & 63;
        ldsL[i] = W2l[c * HID + k];
        ldsR[i] = W2r[c * HID + k];
    }
    __syncthreads();
    int lane = threadIdx.x & 63;
    int g = lane >> 4, c4 = lane & 15;
    float4 sc = *(const float4*)(sc1 + 4 * c4);
    float4 sh = *(const float4*)(sh1 + 4 * c4);
    float4 bb = *(const float4*)(b2l + 4 * c4);
    int wv = blockIdx.x * 4 + (threadIdx.x >> 6);
    int nw = gridDim.x * 4;
    float ps0 = 0, ps1 = 0, ps2 = 0, ps3 = 0, pq0 = 0, pq1 = 0, pq2 = 0, pq3 = 0;
    for (int t = wv; t < NN / 8; t += nw) {
        int nA = t * 8 + 2 * g;
        int r0 = rowptr[nA], r1 = rowptr[nA + 1], r2 = rowptr[nA + 2];
        float invA = 1.f / fmaxf((float)(r1 - r0), 1.f);
        float invB = 1.f / fmaxf((float)(r2 - r1), 1.f);
        float4 gA = *(const float4*)(agg2 + (size_t)nA * HID + 4 * c4);
        float4 gB = *(const float4*)(agg2 + (size_t)(nA + 1) * HID + 4 * c4);
        float4 hA = *(const float4*)(H1 + (size_t)nA * HID + 4 * c4);
        float4 hB = *(const float4*)(H1 + (size_t)(nA + 1) * HID + 4 * c4);
        float4 v1A = {gA.x * invA, gA.y * invA, gA.z * invA, gA.w * invA};
        float4 v1B = {gB.x * invB, gB.y * invB, gB.z * invB, gB.w * invB};
        float4 v2A, v2B;
        v2A.x = fmaxf(fmaf(hA.x, sc.x, sh.x), 0.f);
        v2A.y = fmaxf(fmaf(hA.y, sc.y, sh.y), 0.f);
        v2A.z = fmaxf(fmaf(hA.z, sc.z, sh.z), 0.f);
        v2A.w = fmaxf(fmaf(hA.w, sc.w, sh.w), 0.f);
        v2B.x = fmaxf(fmaf(hB.x, sc.x, sh.x), 0.f);
        v2B.y = fmaxf(fmaf(hB.y, sc.y, sh.y), 0.f);
        v2B.z = fmaxf(fmaf(hB.z, sc.z, sh.z), 0.f);
        v2B.w = fmaxf(fmaf(hB.w, sc.w, sh.w), 0.f);
        float oA0 = 0, oA1 = 0, oA2 = 0, oA3 = 0;
        float oB0 = 0, oB1 = 0, oB2 = 0, oB3 = 0;
#pragma unroll
        for (int k = 0; k < HID; ++k) {
            int srcl = (g << 4) | (k >> 2);
            float a1v = __shfl(PICK(v1A, k & 3), srcl);
            float a2v = __shfl(PICK(v2A, k & 3), srcl);
            float b1v = __shfl(PICK(v1B, k & 3), srcl);
            float b2v = __shfl(PICK(v2B, k & 3), srcl);
            const float4 wl = *(const float4*)(ldsL + k * HID + 4 * c4);
            const float4 wr = *(const float4*)(ldsR + k * HID + 4 * c4);
            oA0 = fmaf(wl.x, a1v, fmaf(wr.x, a2v, oA0));
            oA1 = fmaf(wl.y, a1v, fmaf(wr.y, a2v, oA1));
            oA2 = fmaf(wl.z, a1v, fmaf(wr.z, a2v, oA2));
            oA3 = fmaf(wl.w, a1v, fmaf(wr.w, a2v, oA3));
            oB0 = fmaf(wl.x, b1v, fmaf(wr.x, b2v, oB0));
            oB1 = fmaf(wl.y, b1v, fmaf(wr.y, b2v, oB1));
            oB2 = fmaf(wl.z, b1v, fmaf(wr.z, b2v, oB2));
            oB3 = fmaf(wl.w, b1v, fmaf(wr.w, b2v, oB3));
        }
        oA0 += bb.x; oA1 += bb.y; oA2 += bb.z; oA3 += bb.w;
        oB0 += bb.x; oB1 += bb.y; oB2 += bb.z; oB3 += bb.w;
        float4 oA = {oA0, oA1, oA2, oA3};
        float4 oB = {oB0, oB1, oB2, oB3};
        *(float4*)(h2 + (size_t)nA * HID + 4 * c4) = oA;
        *(float4*)(h2 + (size_t)(nA + 1) * HID + 4 * c4) = oB;
        ps0 += oA0 + oB0; ps1 += oA1 + oB1; ps2 += oA2 + oB2; ps3 += oA3 + oB3;
        pq0 += oA0 * oA0 + oB0 * oB0; pq1 += oA1 * oA1 + oB1 * oB1;
        pq2 += oA2 * oA2 + oB2 * oB2; pq3 += oA3 * oA3 + oB3 * oB3;
    }
    __shared__ float bs[HID], bq[HID];
    if (threadIdx.x < HID) { bs[threadIdx.x] = 0.f; bq[threadIdx.x] = 0.f; }
    __syncthreads();
    atomicAdd(&bs[4 * c4 + 0], ps0); atomicAdd(&bq[4 * c4 + 0], pq0);
    atomicAdd(&bs[4 * c4 + 1], ps1); atomicAdd(&bq[4 * c4 + 1], pq1);
    atomicAdd(&bs[4 * c4 + 2], ps2); atomicAdd(&bq[4 * c4 + 2], pq2);
    atomicAdd(&bs[4 * c4 + 3], ps3); atomicAdd(&bq[4 * c4 + 3], pq3);
    __syncthreads();
    if (threadIdx.x < HID) {
        atomicAdd(&gsum[threadIdx.x], bs[threadIdx.x]);
        atomicAdd(&gsq[threadIdx.x], bq[threadIdx.x]);
    }
}

// ---------------- output head ----------------

__global__ void kJ_out_r6(const float* __restrict__ H2,
                          const float* __restrict__ sc2, const float* __restrict__ sh2,
                          const float* __restrict__ Wc, const float* __restrict__ bc,
                          float* __restrict__ out) {
    int lane = threadIdx.x & 63;
    int g = lane >> 4, c4 = lane & 15;
    int wv = blockIdx.x * 4 + (threadIdx.x >> 6);
    int nw = gridDim.x * 4;
    float4 sc = *(const float4*)(sc2 + 4 * c4);
    float4 sh = *(const float4*)(sh2 + 4 * c4);
    float4 w0 = *(const float4*)(Wc + 4 * c4);
    float4 w1 = *(const float4*)(Wc + HID + 4 * c4);
    float b0 = bc[0], b1 = bc[1];
    for (int t = wv; t < NN / 4; t += nw) {
        int n = t * 4 + g;
        float4 h = *(const float4*)(H2 + (size_t)n * HID + 4 * c4);
        float vx = fmaxf(fmaf(h.x, sc.x, sh.x), 0.f);
        float vy = fmaxf(fmaf(h.y, sc.y, sh.y), 0.f);
        float vz = fmaxf(fmaf(h.z, sc.z, sh.z), 0.f);
        float vw = fmaxf(fmaf(h.w, sc.w, sh.w), 0.f);
        float r0 = vx * w0.x + vy * w0.y + vz * w0.z + vw * w0.w;
        float r1 = vx * w1.x + vy * w1.y + vz * w1.z + vw * w1.w;
#pragma unroll
        for (int off = 1; off <= 8; off <<= 1) {
            r0 += __shfl_xor(r0, off);
            r1 += __shfl_xor(r1, off);
        }
        if (c4 == 0) {
            out[(size_t)n * 2] = r0 + b0;
            out[(size_t)n * 2 + 1] = r1 + b1;
        }
    }
}

// ---------------- host launcher ----------------

extern "C" void kernel_launch(void* const* d_in, const int* in_sizes, int n_in,
                              void* d_out, int out_size, void* d_ws, size_t ws_size,
                              hipStream_t stream) {
    const float* x = (const float*)d_in[0];
    const int* ei = (const int*)d_in[1];
    const float* eattr = (const float*)d_in[2];
    const float* We = (const float*)d_in[3];
    const float* be = (const float*)d_in[4];
    const float* W1l = (const float*)d_in[5];
    const float* b1l = (const float*)d_in[6];
    const float* W1r = (const float*)d_in[7];
    const float* W2l = (const float*)d_in[8];
    const float* b2l = (const float*)d_in[9];
    const float* W2r = (const float*)d_in[10];
    const float* g1 = (const float*)d_in[11];
    const float* beta1 = (const float*)d_in[12];
    const float* g2 = (const float*)d_in[13];
    const float* beta2 = (const float*)d_in[14];
    const float* Wc = (const float*)d_in[15];
    const float* bc = (const float*)d_in[16];
    float* out = (float*)d_out;

    const int* e_src = ei;
    const int* e_dst = ei + NE;

    char* ws = (char*)d_ws;
    size_t off = 0;
    auto alloc = [&](size_t b) {
        char* p = ws + off;
        off += (b + 255) & ~(size_t)255;
        return p;
    };
    int* rowptr = (int*)alloc((NN + 1) * sizeof(int));
    int* cnt = (int*)alloc(NN * sizeof(int));
    float4* pack = (float4*)alloc((size_t)NE * 16);        // 51.2MB: pack -> agg2(front)+h2(back)
    char* bufD = alloc((size_t)NE * sizeof(int));          // 12.8MB: slot -> xp -> csr_src
    float* ax = (float*)alloc((size_t)NN * 32 * sizeof(float));  // 12.8MB
    float* H1 = (float*)alloc((size_t)NN * HID * sizeof(float)); // 25.6MB: eagg -> h1
    float* stats = (float*)alloc(512 * sizeof(float));
    float* gsum1 = stats, *gsq1 = stats + 64, *gsum2 = stats + 128, *gsq2 = stats + 192;
    float* scale1 = stats + 256, *shift1 = stats + 320;
    float* scale2 = stats + 384, *shift2 = stats + 448;

    int* slot = (int*)bufD;        // live kA -> kC
    float* xp = (float*)bufD;      // live kP -> kG1
    int* csr_src = (int*)bufD;     // live kD -> kG2
    float* agg2 = (float*)pack;                               // front 25.6MB, live kG2 -> kQ2
    float* h2 = (float*)((char*)pack + (size_t)NN * HID * 4); // back 25.6MB, live kQ2 -> kJ

    hipMemsetAsync(cnt, 0, NN * sizeof(int), stream);
    hipMemsetAsync(stats, 0, 256 * sizeof(float), stream);

    kA_count_r6<<<2048, 256, 0, stream>>>(e_dst, cnt, slot);
    kB_scan_r6<<<1, 1024, 0, stream>>>(cnt, rowptr);
    kC_fill_r6<<<2048, 256, 0, stream>>>(e_src, e_dst, eattr, rowptr, slot, pack);
    kP_pad_r6<<<1024, 256, 0, stream>>>(x, xp);
    kG1_gather_r6<<<4096, 256, 0, stream>>>(pack, (const float4*)xp, rowptr, We, be,
                                            H1, (float4*)ax);
    kD_strip_r6<<<2048, 256, 0, stream>>>((const int4*)pack, csr_src);
    kQ1_post_r6<<<2048, 256, 0, stream>>>(x, ax, W1l, b1l, W1r, rowptr, H1, gsum1, gsq1);
    kG_bnstat_r6<<<1, 64, 0, stream>>>(gsum1, gsq1, g1, beta1, scale1, shift1);
    kG2_gather_r6<<<4096, 256, 0, stream>>>(H1, csr_src, rowptr, scale1, shift1, agg2);
    kQ2_post_r6<<<2048, 256, 0, stream>>>(H1, agg2, rowptr, W2l, W2r, b2l,
                                          scale1, shift1, h2, gsum2, gsq2);
    kG_bnstat_r6<<<1, 64, 0, stream>>>(gsum2, gsq2, g2, beta2, scale2, shift2);
    kJ_out_r6<<<512, 256, 0, stream>>>(h2, scale2, shift2, Wc, bc, out);
}